// Round 4
// baseline (3574.319 us; speedup 1.0000x reference)
//
#include <hip/hip_runtime.h>
#include <math.h>

#define B_    2
#define S_    2048
#define M_TOT 4096
#define DIM_  2048
#define NH_   16
#define QL_   1536
#define KVL_  512
#define QKN_  128
#define QKR_  64
#define VH_   128
#define QKH_  192
#define QSTR  3072      // NH_*QKH_
#define QP_STR 584      // padded LDS row stride for resident Q (576+8)

typedef short s16x8 __attribute__((ext_vector_type(8)));
typedef float f32x4 __attribute__((ext_vector_type(4)));
typedef unsigned short u16;
#define AS1 __attribute__((address_space(1)))
#define AS3 __attribute__((address_space(3)))

__device__ inline u16 f2bf(float f) {
    unsigned u = __float_as_uint(f);
    unsigned r = u + 0x7FFFu + ((u >> 16) & 1u);   // round-to-nearest-even
    return (u16)(r >> 16);
}
__device__ inline float bf2f(u16 h) { return __uint_as_float(((unsigned)h) << 16); }

// ---------------------------------------------------------------------------
// m97-pattern bf16 MFMA GEMM (known good since round 2).
// ---------------------------------------------------------------------------
__global__ __launch_bounds__(256)
void gemm_bf16(const u16* __restrict__ A, const u16* __restrict__ Bm,
               const float* __restrict__ bias, void* __restrict__ Cv,
               int M, int N, int K, int ldA, int ldB, int ldC,
               long long sAz, long long sBz, long long sCz,
               float alpha, int outF32)
{
    __shared__ u16 As[128 * 32];
    __shared__ u16 Bs[128 * 32];
    const int tid = threadIdx.x;
    const int w = tid >> 6, l = tid & 63;
    const int m0 = blockIdx.y * 128, n0 = blockIdx.x * 128;
    const int z = blockIdx.z;
    const u16* Az = A + (size_t)z * sAz;
    const u16* Bz = Bm + (size_t)z * sBz;

    const int rin = l >> 2;
    const int cel = (l & 3) * 8;
    const int lane15 = l & 15, quad = l >> 4;
    const int wm = w & 1, wn = w >> 1;

    f32x4 acc[4][4] = {};

    for (int k0 = 0; k0 < K; k0 += 32) {
        __syncthreads();
        #pragma unroll
        for (int c = 0; c < 2; ++c) {
            const int chunk = w * 2 + c;
            const int rowA = m0 + chunk * 16 + rin;
            const u16* ga = Az + (size_t)rowA * ldA + k0 + cel;
            u16* la = &As[chunk * 512 + rin * 32 + cel];
            __builtin_amdgcn_global_load_lds((const AS1 unsigned*)ga, (AS3 unsigned*)la, 16, 0, 0);
            int rowB = n0 + chunk * 16 + rin;
            if (rowB > N - 1) rowB = N - 1;
            const u16* gb = Bz + (size_t)rowB * ldB + k0 + cel;
            u16* lb = &Bs[chunk * 512 + rin * 32 + cel];
            __builtin_amdgcn_global_load_lds((const AS1 unsigned*)gb, (AS3 unsigned*)lb, 16, 0, 0);
        }
        __syncthreads();
        s16x8 af[4], bf[4];
        #pragma unroll
        for (int i = 0; i < 4; ++i)
            af[i] = *(const s16x8*)&As[(wm * 64 + i * 16 + lane15) * 32 + quad * 8];
        #pragma unroll
        for (int i = 0; i < 4; ++i)
            bf[i] = *(const s16x8*)&Bs[(wn * 64 + i * 16 + lane15) * 32 + quad * 8];
        #pragma unroll
        for (int mi = 0; mi < 4; ++mi)
            #pragma unroll
            for (int ni = 0; ni < 4; ++ni)
                acc[mi][ni] = __builtin_amdgcn_mfma_f32_16x16x32_bf16(af[mi], bf[ni], acc[mi][ni], 0, 0, 0);
    }

    const int cmb = m0 + wm * 64, cnb = n0 + wn * 64;
    if (outF32) {
        float* C = (float*)Cv + (size_t)z * sCz;
        #pragma unroll
        for (int mi = 0; mi < 4; ++mi)
            #pragma unroll
            for (int ni = 0; ni < 4; ++ni) {
                const int nn = cnb + ni * 16 + lane15;
                if (nn < N) {
                    const float bv = bias ? bias[nn] : 0.f;
                    #pragma unroll
                    for (int r = 0; r < 4; ++r) {
                        const int mm = cmb + mi * 16 + quad * 4 + r;
                        C[(size_t)mm * ldC + nn] = acc[mi][ni][r] * alpha + bv;
                    }
                }
            }
    } else {
        u16* C = (u16*)Cv + (size_t)z * sCz;
        #pragma unroll
        for (int mi = 0; mi < 4; ++mi)
            #pragma unroll
            for (int ni = 0; ni < 4; ++ni) {
                const int nn = cnb + ni * 16 + lane15;
                if (nn < N) {
                    const float bv = bias ? bias[nn] : 0.f;
                    #pragma unroll
                    for (int r = 0; r < 4; ++r) {
                        const int mm = cmb + mi * 16 + quad * 4 + r;
                        C[(size_t)mm * ldC + nn] = f2bf(acc[mi][ni][r] * alpha + bv);
                    }
                }
            }
    }
}

// ---------------------------------------------------------------------------
// Flash v2: 512 thr (8 waves) per (b, h, 64-q-row tile). Q resident in LDS.
// k-tiles of 512 keys; wave tile 64q x 64k (4x4 of 16x16x32 MFMA).
// Score: 18 K-chunks (32 dims), double-buffered global_load_lds, 1 barrier/chunk.
// Softmax: shuffle + cross-wave LDS reduce. PV: 16 t-chunks of 32 keys,
// V double-buffered in same LDS as K; P fed via small double-buffered LDS piece.
// Output overwrites Qpack[..., 0:512] (block-local rows).
// LDS: 74752(Q) + 65536(K/V dbuf) + 10240(P dbuf) + 3072(reduce) = 153600 B.
// ---------------------------------------------------------------------------
__global__ __launch_bounds__(512, 2)
void mla_flash(u16* __restrict__ Qp, const u16* __restrict__ Kcat,
               const u16* __restrict__ KVT)
{
    __shared__ u16 sQ[64 * QP_STR];
    __shared__ u16 sKV[2][512 * 32];
    __shared__ u16 sPc[2][64 * 40];
    __shared__ float sR[64 * 8];
    __shared__ float sM[64], sL[64], sAl[64], sMn[64];

    const int tid = threadIdx.x;
    const int w = tid >> 6, l = tid & 63;
    const int lane15 = l & 15, quad = l >> 4;
    const int qt = 31 - blockIdx.x;            // heavy tiles first
    const int h = blockIdx.y, b = blockIdx.z;
    const int qs = qt * 64;
    u16* Qrow = Qp + ((size_t)h * M_TOT + b * S_ + qs) * 576;
    const float scale = 0.07216878364870323f;  // 1/sqrt(192)

    // ---- load Q tile resident (64 x 576, coalesced 16B) ----
    {
        const int r = tid >> 3, c0 = (tid & 7) * 8;
        #pragma unroll
        for (int jj = 0; jj < 9; ++jj) {
            const int c = c0 + jj * 64;
            *(s16x8*)&sQ[r * QP_STR + c] = *(const s16x8*)&Qrow[(size_t)r * 576 + c];
        }
    }
    if (tid < 64) { sM[tid] = -1e30f; sL[tid] = 0.f; }

    f32x4 Oacc[4][4] = {};                     // 64q x (w's 64 c-cols)
    const int ktiles = (qs + 64 + 511) >> 9;
    const int keyr = l >> 2;                   // + jj*128 + w*16
    const int t8 = (l & 3) * 8;

    for (int kt0 = 0; kt0 < ktiles; ++kt0) {
        const int kt = kt0 << 9;
        f32x4 Sacc[4][4] = {};

        __syncthreads();                       // prev phase done; Q fill done
        // prefetch K chunk 0
        #pragma unroll
        for (int jj = 0; jj < 4; ++jj) {
            const int key = jj * 128 + w * 16 + keyr;
            const u16* g = Kcat + (size_t)(b * S_ + kt + key) * 576 + t8;
            u16* ld = &sKV[0][key * 32 + t8];
            __builtin_amdgcn_global_load_lds((const AS1 unsigned*)g, (AS3 unsigned*)ld, 16, 0, 0);
        }
        // ---- score: S(64x512) = Q(64x576) . K(512x576)^T ----
        #pragma unroll 1
        for (int j = 0; j < 18; ++j) {
            const int cur = j & 1;
            __syncthreads();                   // drains loads for chunk j
            if (j < 17) {
                const int k0n = (j + 1) * 32;
                #pragma unroll
                for (int jj = 0; jj < 4; ++jj) {
                    const int key = jj * 128 + w * 16 + keyr;
                    const u16* g = Kcat + (size_t)(b * S_ + kt + key) * 576 + k0n + t8;
                    u16* ld = &sKV[cur ^ 1][key * 32 + t8];
                    __builtin_amdgcn_global_load_lds((const AS1 unsigned*)g, (AS3 unsigned*)ld, 16, 0, 0);
                }
            }
            const int k0 = j * 32;
            s16x8 af[4], bf[4];
            #pragma unroll
            for (int mi = 0; mi < 4; ++mi)
                af[mi] = *(const s16x8*)&sQ[(mi * 16 + lane15) * QP_STR + k0 + quad * 8];
            #pragma unroll
            for (int ni = 0; ni < 4; ++ni)
                bf[ni] = *(const s16x8*)&sKV[cur][(w * 64 + ni * 16 + lane15) * 32 + quad * 8];
            #pragma unroll
            for (int mi = 0; mi < 4; ++mi)
                #pragma unroll
                for (int ni = 0; ni < 4; ++ni)
                    Sacc[mi][ni] = __builtin_amdgcn_mfma_f32_16x16x32_bf16(af[mi], bf[ni], Sacc[mi][ni], 0, 0, 0);
        }

        // ---- scale + causal mask + row max (16-lane shuffle, cross-wave LDS) ----
        #pragma unroll
        for (int mi = 0; mi < 4; ++mi)
            #pragma unroll
            for (int r = 0; r < 4; ++r) {
                const int rowg = qs + mi * 16 + quad * 4 + r;
                float mx = -1e30f;
                #pragma unroll
                for (int ni = 0; ni < 4; ++ni) {
                    const int colg = kt + w * 64 + ni * 16 + lane15;
                    float v = Sacc[mi][ni][r] * scale;
                    v = (colg <= rowg) ? v : -1e30f;
                    Sacc[mi][ni][r] = v;
                    mx = fmaxf(mx, v);
                }
                #pragma unroll
                for (int sh = 1; sh < 16; sh <<= 1) mx = fmaxf(mx, __shfl_xor(mx, sh));
                if (lane15 == 0) sR[(mi * 16 + quad * 4 + r) * 8 + w] = mx;
            }
        __syncthreads();
        if (tid < 64) {
            const float m_old = sM[tid];
            float mn = m_old;
            #pragma unroll
            for (int ww = 0; ww < 8; ++ww) mn = fmaxf(mn, sR[tid * 8 + ww]);
            sMn[tid] = mn; sAl[tid] = __expf(m_old - mn); sM[tid] = mn;
        }
        __syncthreads();

        // ---- P = exp(S-m) in regs, rescale O, partial row sums ----
        #pragma unroll
        for (int mi = 0; mi < 4; ++mi)
            #pragma unroll
            for (int r = 0; r < 4; ++r) {
                const int rowl = mi * 16 + quad * 4 + r;
                const float mn = sMn[rowl], al = sAl[rowl];
                float sum = 0.f;
                #pragma unroll
                for (int ni = 0; ni < 4; ++ni) {
                    const float p = __expf(Sacc[mi][ni][r] - mn);
                    Sacc[mi][ni][r] = p;
                    sum += p;
                }
                #pragma unroll
                for (int ci = 0; ci < 4; ++ci) Oacc[mi][ci][r] *= al;
                #pragma unroll
                for (int sh = 1; sh < 16; sh <<= 1) sum += __shfl_xor(sum, sh);
                if (lane15 == 0) sR[rowl * 8 + w] = sum;
            }
        __syncthreads();                       // sR ready; score reads of sKV done
        if (tid < 64) {
            float s = 0.f;
            #pragma unroll
            for (int ww = 0; ww < 8; ++ww) s += sR[tid * 8 + ww];
            sL[tid] = sL[tid] * sAl[tid] + s;
        }
        // PV prologue: owner of tc=0 (wave 0) writes sPc[0]; all issue V chunk 0
        if (w == 0) {
            #pragma unroll
            for (int mi = 0; mi < 4; ++mi)
                #pragma unroll
                for (int nio = 0; nio < 2; ++nio)
                    #pragma unroll
                    for (int r = 0; r < 4; ++r)
                        sPc[0][(mi * 16 + quad * 4 + r) * 40 + nio * 16 + lane15] =
                            f2bf(Sacc[mi][nio][r]);
        }
        #pragma unroll
        for (int jj = 0; jj < 4; ++jj) {
            const int c = jj * 128 + w * 16 + keyr;
            const u16* g = KVT + (size_t)(b * 512 + c) * S_ + kt + t8;
            u16* ld = &sKV[0][c * 32 + t8];
            __builtin_amdgcn_global_load_lds((const AS1 unsigned*)g, (AS3 unsigned*)ld, 16, 0, 0);
        }
        // ---- PV: O(64x512) += P(64x512) . KV(512x512) over 16 t-chunks ----
        #pragma unroll 1
        for (int tc = 0; tc < 16; ++tc) {
            const int cur = tc & 1;
            __syncthreads();                   // drains V[tc] loads + sPc[tc] writes
            if (tc < 15) {
                if (w == ((tc + 1) >> 1)) {
                    const int sub = (tc + 1) & 1;
                    #pragma unroll
                    for (int mi = 0; mi < 4; ++mi)
                        #pragma unroll
                        for (int nio = 0; nio < 2; ++nio)
                            #pragma unroll
                            for (int r = 0; r < 4; ++r)
                                sPc[cur ^ 1][(mi * 16 + quad * 4 + r) * 40 + nio * 16 + lane15] =
                                    f2bf(Sacc[mi][sub * 2 + nio][r]);
                }
                #pragma unroll
                for (int jj = 0; jj < 4; ++jj) {
                    const int c = jj * 128 + w * 16 + keyr;
                    const u16* g = KVT + (size_t)(b * 512 + c) * S_ + kt + (tc + 1) * 32 + t8;
                    u16* ld = &sKV[cur ^ 1][c * 32 + t8];
                    __builtin_amdgcn_global_load_lds((const AS1 unsigned*)g, (AS3 unsigned*)ld, 16, 0, 0);
                }
            }
            s16x8 pf[4], vf[4];
            #pragma unroll
            for (int mi = 0; mi < 4; ++mi)
                pf[mi] = *(const s16x8*)&sPc[cur][(mi * 16 + lane15) * 40 + quad * 8];
            #pragma unroll
            for (int ci = 0; ci < 4; ++ci)
                vf[ci] = *(const s16x8*)&sKV[cur][(w * 64 + ci * 16 + lane15) * 32 + quad * 8];
            #pragma unroll
            for (int mi = 0; mi < 4; ++mi)
                #pragma unroll
                for (int ci = 0; ci < 4; ++ci)
                    Oacc[mi][ci] = __builtin_amdgcn_mfma_f32_16x16x32_bf16(pf[mi], vf[ci], Oacc[mi][ci], 0, 0, 0);
        }
    }

    // ---- epilogue: O/l -> bf16, overwrite Qpack[..., 0:512] ----
    __syncthreads();
    #pragma unroll
    for (int mi = 0; mi < 4; ++mi)
        #pragma unroll
        for (int r = 0; r < 4; ++r) {
            const int rowl = mi * 16 + quad * 4 + r;
            const float inv = 1.f / sL[rowl];
            #pragma unroll
            for (int ci = 0; ci < 4; ++ci)
                Qrow[(size_t)rowl * 576 + w * 64 + ci * 16 + lane15] =
                    f2bf(Oacc[mi][ci][r] * inv);
        }
}

// ---------------------------------------------------------------------------
__global__ __launch_bounds__(256)
void cast_f32_bf16(const float* __restrict__ src, u16* __restrict__ dst, int n)
{
    for (int i = blockIdx.x * 256 + threadIdx.x; i < n; i += gridDim.x * 256)
        dst[i] = f2bf(src[i]);
}

__global__ __launch_bounds__(256)
void prep_wbnT(const float* __restrict__ wkvb, u16* __restrict__ dst)
{
    int i = blockIdx.x * 256 + threadIdx.x;
    int h = i >> 16, rem = i & 65535, c = rem >> 7, d = rem & 127;
    dst[i] = f2bf(wkvb[(size_t)(h * 256 + d) * 512 + c]);
}

__global__ __launch_bounds__(256)
void prep_wbv(const float* __restrict__ wkvb, u16* __restrict__ dst)
{
    int i = blockIdx.x * 256 + threadIdx.x;
    int h = i >> 16, rem = i & 65535;
    dst[i] = f2bf(wkvb[(size_t)h * 131072 + 65536 + rem]);
}

__global__ __launch_bounds__(256)
void rmsnorm_bf16(u16* __restrict__ X, const float* __restrict__ w, int D)
{
    const int m = blockIdx.x;
    u16* x = X + (size_t)m * D;
    float ss = 0.f;
    for (int k = threadIdx.x; k < D; k += 256) { float v = bf2f(x[k]); ss += v * v; }
    __shared__ float red[256];
    red[threadIdx.x] = ss; __syncthreads();
    for (int s = 128; s > 0; s >>= 1) {
        if (threadIdx.x < s) red[threadIdx.x] += red[threadIdx.x + s];
        __syncthreads();
    }
    const float sc = rsqrtf(red[0] / (float)D + 1e-6f);
    for (int k = threadIdx.x; k < D; k += 256) x[k] = f2bf(bf2f(x[k]) * sc * w[k]);
}

// q (bf16, rows QSTR) -> rotate q_pe, write to Qpack[h][m][512:576]
__global__ __launch_bounds__(256)
void rope_q(const u16* __restrict__ q, const float* __restrict__ freqs, u16* __restrict__ Qp)
{
    const int idx = blockIdx.x * 256 + threadIdx.x;
    const int i = idx & 31, h = (idx >> 5) & 15, m = idx >> 9;
    const int s = m & (S_ - 1);
    const float c = freqs[(s * 32 + i) * 2], sn = freqs[(s * 32 + i) * 2 + 1];
    const u16* src = q + (size_t)m * QSTR + h * QKH_ + QKN_ + 2 * i;
    const float x0 = bf2f(src[0]), x1 = bf2f(src[1]);
    u16* dst = Qp + ((size_t)h * M_TOT + m) * 576 + 512 + 2 * i;
    dst[0] = f2bf(x0 * c - x1 * sn);
    dst[1] = f2bf(x1 * c + x0 * sn);
}

__global__ __launch_bounds__(256)
void kv_norm_rope(const u16* __restrict__ kva, const float* __restrict__ w,
                  const float* __restrict__ freqs, u16* __restrict__ Kcat)
{
    const int m = blockIdx.x, s = m & (S_ - 1);
    const u16* x = kva + (size_t)m * 576;
    float ss = 0.f;
    for (int k = threadIdx.x; k < 512; k += 256) { float v = bf2f(x[k]); ss += v * v; }
    __shared__ float red[256];
    red[threadIdx.x] = ss; __syncthreads();
    for (int st = 128; st > 0; st >>= 1) {
        if (threadIdx.x < st) red[threadIdx.x] += red[threadIdx.x + st];
        __syncthreads();
    }
    const float sc = rsqrtf(red[0] / 512.f + 1e-6f);
    for (int k = threadIdx.x; k < 512; k += 256)
        Kcat[(size_t)m * 576 + k] = f2bf(bf2f(x[k]) * sc * w[k]);
    if (threadIdx.x < 32) {
        const int i = threadIdx.x;
        const float c = freqs[(s * 32 + i) * 2], sn = freqs[(s * 32 + i) * 2 + 1];
        const float x0 = bf2f(x[512 + 2 * i]), x1 = bf2f(x[512 + 2 * i + 1]);
        Kcat[(size_t)m * 576 + 512 + 2 * i]     = f2bf(x0 * c - x1 * sn);
        Kcat[(size_t)m * 576 + 512 + 2 * i + 1] = f2bf(x1 * c + x0 * sn);
    }
}

__global__ __launch_bounds__(256)
void transpose_kv(const u16* __restrict__ Kcat, u16* __restrict__ KVT)
{
    __shared__ u16 t[64][65];
    const int s0 = blockIdx.x * 64, c0 = blockIdx.y * 64, b = blockIdx.z;
    #pragma unroll
    for (int i = 0; i < 16; ++i) {
        int id = i * 256 + threadIdx.x, r = id >> 6, c = id & 63;
        t[r][c] = Kcat[(size_t)(b * S_ + s0 + r) * 576 + c0 + c];
    }
    __syncthreads();
    #pragma unroll
    for (int i = 0; i < 16; ++i) {
        int id = i * 256 + threadIdx.x, r = id >> 6, c = id & 63;
        KVT[(size_t)(b * 512 + c0 + r) * S_ + s0 + c] = t[c][r];
    }
}

// ---------------------------------------------------------------------------
extern "C" void kernel_launch(void* const* d_in, const int* in_sizes, int n_in,
                              void* d_out, int out_size, void* d_ws, size_t ws_size,
                              hipStream_t stream)
{
    (void)in_sizes; (void)n_in; (void)out_size; (void)ws_size;
    const float* x         = (const float*)d_in[0];
    const float* freqs     = (const float*)d_in[1];
    const float* wq_a_w    = (const float*)d_in[4];
    const float* wq_a_b    = (const float*)d_in[5];
    const float* q_norm_w  = (const float*)d_in[6];
    const float* wq_b_w    = (const float*)d_in[7];
    const float* wq_b_b    = (const float*)d_in[8];
    const float* wkv_a_w   = (const float*)d_in[9];
    const float* wkv_a_b   = (const float*)d_in[10];
    const float* kv_norm_w = (const float*)d_in[11];
    const float* wkv_b_w   = (const float*)d_in[12];
    const float* wo_w      = (const float*)d_in[13];
    const float* wo_b      = (const float*)d_in[14];
    float* out = (float*)d_out;

    char* W = (char*)d_ws;
    u16* x_bf  = (u16*)(W + 0);
    u16* wqa   = (u16*)(W + 16777216);
    u16* wqb   = (u16*)(W + 23068672);
    u16* wkva  = (u16*)(W + 32505856);
    u16* wobf  = (u16*)(W + 34865152);
    u16* wbnT  = (u16*)(W + 43253760);
    u16* wbv   = (u16*)(W + 45350912);
    u16* q_a   = (u16*)(W + 47448064);
    u16* q     = (u16*)(W + 60030976);
    u16* kv_a  = (u16*)(W + 85196800);
    u16* Kcat  = (u16*)(W + 89915392);
    u16* KVT   = (u16*)(W + 94633984);
    u16* Qp    = (u16*)(W + 98828288);   // Qpack[h][4096][576]: q_abs|q_pe -> attn out
    u16* outh  = (u16*)(W + 174325760);

    const dim3 blk(256);

    // --- dtype prep ---
    cast_f32_bf16<<<2048, blk, 0, stream>>>(x, x_bf, M_TOT * DIM_);
    cast_f32_bf16<<<2048, blk, 0, stream>>>(wq_a_w, wqa, QL_ * DIM_);
    cast_f32_bf16<<<2048, blk, 0, stream>>>(wq_b_w, wqb, QSTR * QL_);
    cast_f32_bf16<<<2048, blk, 0, stream>>>(wkv_a_w, wkva, 576 * DIM_);
    cast_f32_bf16<<<2048, blk, 0, stream>>>(wo_w, wobf, DIM_ * DIM_);
    prep_wbnT<<<4096, blk, 0, stream>>>(wkv_b_w, wbnT);
    prep_wbv<<<4096, blk, 0, stream>>>(wkv_b_w, wbv);

    // --- q path ---
    gemm_bf16<<<dim3(12, 32, 1), blk, 0, stream>>>(x_bf, wqa, wq_a_b, q_a,
        M_TOT, QL_, DIM_, DIM_, DIM_, QL_, 0, 0, 0, 1.f, 0);
    rmsnorm_bf16<<<M_TOT, blk, 0, stream>>>(q_a, q_norm_w, QL_);
    gemm_bf16<<<dim3(24, 32, 1), blk, 0, stream>>>(q_a, wqb, wq_b_b, q,
        M_TOT, QSTR, QL_, QL_, QL_, QSTR, 0, 0, 0, 1.f, 0);
    rope_q<<<(M_TOT * NH_ * 32) / 256, blk, 0, stream>>>(q, freqs, Qp);

    // --- kv path ---
    gemm_bf16<<<dim3(5, 32, 1), blk, 0, stream>>>(x_bf, wkva, wkv_a_b, kv_a,
        M_TOT, 576, DIM_, DIM_, DIM_, 576, 0, 0, 0, 1.f, 0);
    kv_norm_rope<<<M_TOT, blk, 0, stream>>>(kv_a, kv_norm_w, freqs, Kcat);
    transpose_kv<<<dim3(32, 8, 2), blk, 0, stream>>>(Kcat, KVT);

    // --- q absorb: Qpack[h][m][0:512] = q_nope @ wkv_b[h,:128,:] ---
    gemm_bf16<<<dim3(4, 32, 16), blk, 0, stream>>>(q, wbnT, nullptr, Qp,
        M_TOT, 512, 128, QSTR, 128, 576, QKH_, 65536, (long long)M_TOT * 576, 1.f, 0);

    // --- fused flash attention v2 ---
    mla_flash<<<dim3(32, 16, 2), dim3(512), 0, stream>>>(Qp, Kcat, KVT);

    // --- V projection: outh[m][h*128+d] = O[h][m][:] . wbv[h][d][:] ---
    gemm_bf16<<<dim3(1, 32, 16), blk, 0, stream>>>(Qp, wbv, nullptr, outh,
        M_TOT, VH_, 512, 576, 512, DIM_, (long long)M_TOT * 576, 65536, VH_, 1.f, 0);

    // --- output projection (fp32 out) ---
    gemm_bf16<<<dim3(16, 32, 1), blk, 0, stream>>>(outh, wobf, wo_b, out,
        M_TOT, DIM_, DIM_, DIM_, DIM_, DIM_, 0, 0, 0, 1.f, 1);
}

// Round 5
// 1327.452 us; speedup vs baseline: 2.6926x; 2.6926x over previous
//
#include <hip/hip_runtime.h>
#include <math.h>

#define B_    2
#define S_    2048
#define M_TOT 4096
#define DIM_  2048
#define NH_   16
#define QL_   1536
#define KVL_  512
#define QKN_  128
#define QKR_  64
#define VH_   128
#define QKH_  192
#define QSTR  3072      // NH_*QKH_
#define QP_STR 584      // padded LDS row stride for resident Q (576+8)

typedef short s16x8 __attribute__((ext_vector_type(8)));
typedef float f32x4 __attribute__((ext_vector_type(4)));
typedef unsigned short u16;
#define AS1 __attribute__((address_space(1)))
#define AS3 __attribute__((address_space(3)))

__device__ inline u16 f2bf(float f) {
    unsigned u = __float_as_uint(f);
    unsigned r = u + 0x7FFFu + ((u >> 16) & 1u);   // round-to-nearest-even
    return (u16)(r >> 16);
}
__device__ inline float bf2f(u16 h) { return __uint_as_float(((unsigned)h) << 16); }

// ---------------------------------------------------------------------------
// m97-pattern bf16 MFMA GEMM (known good since round 2).
// ---------------------------------------------------------------------------
__global__ __launch_bounds__(256)
void gemm_bf16(const u16* __restrict__ A, const u16* __restrict__ Bm,
               const float* __restrict__ bias, void* __restrict__ Cv,
               int M, int N, int K, int ldA, int ldB, int ldC,
               long long sAz, long long sBz, long long sCz,
               float alpha, int outF32)
{
    __shared__ u16 As[128 * 32];
    __shared__ u16 Bs[128 * 32];
    const int tid = threadIdx.x;
    const int w = tid >> 6, l = tid & 63;
    const int m0 = blockIdx.y * 128, n0 = blockIdx.x * 128;
    const int z = blockIdx.z;
    const u16* Az = A + (size_t)z * sAz;
    const u16* Bz = Bm + (size_t)z * sBz;

    const int rin = l >> 2;
    const int cel = (l & 3) * 8;
    const int lane15 = l & 15, quad = l >> 4;
    const int wm = w & 1, wn = w >> 1;

    f32x4 acc[4][4] = {};

    for (int k0 = 0; k0 < K; k0 += 32) {
        __syncthreads();
        #pragma unroll
        for (int c = 0; c < 2; ++c) {
            const int chunk = w * 2 + c;
            const int rowA = m0 + chunk * 16 + rin;
            const u16* ga = Az + (size_t)rowA * ldA + k0 + cel;
            u16* la = &As[chunk * 512 + rin * 32 + cel];
            __builtin_amdgcn_global_load_lds((const AS1 unsigned*)ga, (AS3 unsigned*)la, 16, 0, 0);
            int rowB = n0 + chunk * 16 + rin;
            if (rowB > N - 1) rowB = N - 1;
            const u16* gb = Bz + (size_t)rowB * ldB + k0 + cel;
            u16* lb = &Bs[chunk * 512 + rin * 32 + cel];
            __builtin_amdgcn_global_load_lds((const AS1 unsigned*)gb, (AS3 unsigned*)lb, 16, 0, 0);
        }
        __syncthreads();
        s16x8 af[4], bf[4];
        #pragma unroll
        for (int i = 0; i < 4; ++i)
            af[i] = *(const s16x8*)&As[(wm * 64 + i * 16 + lane15) * 32 + quad * 8];
        #pragma unroll
        for (int i = 0; i < 4; ++i)
            bf[i] = *(const s16x8*)&Bs[(wn * 64 + i * 16 + lane15) * 32 + quad * 8];
        #pragma unroll
        for (int mi = 0; mi < 4; ++mi)
            #pragma unroll
            for (int ni = 0; ni < 4; ++ni)
                acc[mi][ni] = __builtin_amdgcn_mfma_f32_16x16x32_bf16(af[mi], bf[ni], acc[mi][ni], 0, 0, 0);
    }

    const int cmb = m0 + wm * 64, cnb = n0 + wn * 64;
    if (outF32) {
        float* C = (float*)Cv + (size_t)z * sCz;
        #pragma unroll
        for (int mi = 0; mi < 4; ++mi)
            #pragma unroll
            for (int ni = 0; ni < 4; ++ni) {
                const int nn = cnb + ni * 16 + lane15;
                if (nn < N) {
                    const float bv = bias ? bias[nn] : 0.f;
                    #pragma unroll
                    for (int r = 0; r < 4; ++r) {
                        const int mm = cmb + mi * 16 + quad * 4 + r;
                        C[(size_t)mm * ldC + nn] = acc[mi][ni][r] * alpha + bv;
                    }
                }
            }
    } else {
        u16* C = (u16*)Cv + (size_t)z * sCz;
        #pragma unroll
        for (int mi = 0; mi < 4; ++mi)
            #pragma unroll
            for (int ni = 0; ni < 4; ++ni) {
                const int nn = cnb + ni * 16 + lane15;
                if (nn < N) {
                    const float bv = bias ? bias[nn] : 0.f;
                    #pragma unroll
                    for (int r = 0; r < 4; ++r) {
                        const int mm = cmb + mi * 16 + quad * 4 + r;
                        C[(size_t)mm * ldC + nn] = f2bf(acc[mi][ni][r] * alpha + bv);
                    }
                }
            }
    }
}

// ---------------------------------------------------------------------------
// Flash v3: 512 thr (8 waves) per (b, h, 64 q-rows). Q resident in LDS.
// k-tile = 128 keys. Score: waves = 2(q-half) x 4(k-slice of 32); 9 K-chunks
// of 64 dims (two 32-dim sub-blocks), double-buffered global_load_lds.
// Softmax: shuffle + cross-wave LDS. P tile (64x128 bf16) written to LDS with
// STATIC indices (round-4 dynamic Sacc indexing caused scratch spill: 5.4 GB
// phantom WRITE_SIZE). PV: waves = 2(q-half) x 4(c-slice of 128); V streamed
// in 4 t-chunks of 32 from KVT, double-buffered.
// LDS: 74752(Q) + 65536(K/V dbuf) + 17408(P) + 2048(misc) = 159744 B -> 1 blk/CU.
// Regs/thread: Sacc 16 + Oacc 64 + frags ~40 -> no spill at 256 cap.
// ---------------------------------------------------------------------------
__global__ __launch_bounds__(512)
void mla_flash(u16* __restrict__ Qp, const u16* __restrict__ Kcat,
               const u16* __restrict__ KVT)
{
    __shared__ u16 sQ[64 * QP_STR];          // 74752 B
    __shared__ u16 sKV[2][16384];            // 65536 B (K chunk 16KB / V chunk 32KB)
    __shared__ u16 sP[64 * 136];             // 17408 B
    __shared__ float sR[64 * 4];             // per-row partials from 4 k-slices
    __shared__ float sM[64], sL[64], sAl[64], sMn[64];

    const int tid = threadIdx.x;
    const int w = tid >> 6, l = tid & 63;
    const int lane15 = l & 15, quad = l >> 4;
    const int wq = w & 1;                    // q-half (rows wq*32 ..)
    const int wk = w >> 1;                   // score k-slice / PV c-slice
    const int qt = 31 - blockIdx.x;          // heavy tiles first
    const int h = blockIdx.y, b = blockIdx.z;
    const int qs = qt * 64;
    u16* Qrow = Qp + ((size_t)h * M_TOT + b * S_ + qs) * 576;
    const float scale = 0.07216878364870323f;  // 1/sqrt(192)

    // ---- Q tile resident (64 x 576, coalesced 16B vector loads) ----
    {
        const int r = tid >> 3, c0 = (tid & 7) * 8;
        #pragma unroll
        for (int jj = 0; jj < 9; ++jj) {
            const int c = c0 + jj * 64;
            *(s16x8*)&sQ[r * QP_STR + c] = *(const s16x8*)&Qrow[(size_t)r * 576 + c];
        }
    }
    if (tid < 64) { sM[tid] = -1e30f; sL[tid] = 0.f; }

    f32x4 Oacc[2][8] = {};                   // rows wq*32+mi*16+..., cols wk*128+ci*16+...
    const int ktiles = (qs + 64 + 127) >> 7;
    const int seg8 = (tid & 3) * 8;          // 16B segment within 32-dim row

    for (int kt0 = 0; kt0 < ktiles; ++kt0) {
        const int kt = kt0 << 7;
        f32x4 Sacc[2][2] = {};

        __syncthreads();                     // prev k-tile PV reads done; Q fill done
        // prefetch K chunk 0 (dims 0..63 as two 32-dim sub-blocks)
        #pragma unroll
        for (int kk = 0; kk < 2; ++kk) {
            const int key = tid >> 2;
            const u16* g = Kcat + (size_t)(b * S_ + kt + key) * 576 + kk * 32 + seg8;
            u16* ld = &sKV[0][kk * 4096 + key * 32 + seg8];
            __builtin_amdgcn_global_load_lds((const AS1 unsigned*)g, (AS3 unsigned*)ld, 16, 0, 0);
        }
        // ---- score: S(64x128) = Q . K^T over 9 chunks of 64 dims ----
        #pragma unroll 1
        for (int j = 0; j < 9; ++j) {
            const int cur = j & 1;
            __syncthreads();                 // drain chunk j loads
            if (j < 8) {
                const int k0n = (j + 1) * 64;
                #pragma unroll
                for (int kk = 0; kk < 2; ++kk) {
                    const int key = tid >> 2;
                    const u16* g = Kcat + (size_t)(b * S_ + kt + key) * 576 + k0n + kk * 32 + seg8;
                    u16* ld = &sKV[cur ^ 1][kk * 4096 + key * 32 + seg8];
                    __builtin_amdgcn_global_load_lds((const AS1 unsigned*)g, (AS3 unsigned*)ld, 16, 0, 0);
                }
            }
            #pragma unroll
            for (int kk = 0; kk < 2; ++kk) {
                s16x8 af[2], bf[2];
                #pragma unroll
                for (int mi = 0; mi < 2; ++mi)
                    af[mi] = *(const s16x8*)&sQ[(wq * 32 + mi * 16 + lane15) * QP_STR + j * 64 + kk * 32 + quad * 8];
                #pragma unroll
                for (int ni = 0; ni < 2; ++ni)
                    bf[ni] = *(const s16x8*)&sKV[cur][kk * 4096 + (wk * 32 + ni * 16 + lane15) * 32 + quad * 8];
                #pragma unroll
                for (int mi = 0; mi < 2; ++mi)
                    #pragma unroll
                    for (int ni = 0; ni < 2; ++ni)
                        Sacc[mi][ni] = __builtin_amdgcn_mfma_f32_16x16x32_bf16(af[mi], bf[ni], Sacc[mi][ni], 0, 0, 0);
            }
        }

        // ---- scale + causal mask + wave-local row max ----
        #pragma unroll
        for (int mi = 0; mi < 2; ++mi)
            #pragma unroll
            for (int r = 0; r < 4; ++r) {
                const int rowl = wq * 32 + mi * 16 + quad * 4 + r;
                const int rowg = qs + rowl;
                float mx = -1e30f;
                #pragma unroll
                for (int ni = 0; ni < 2; ++ni) {
                    const int colg = kt + wk * 32 + ni * 16 + lane15;
                    float v = Sacc[mi][ni][r] * scale;
                    v = (colg <= rowg) ? v : -1e30f;
                    Sacc[mi][ni][r] = v;
                    mx = fmaxf(mx, v);
                }
                #pragma unroll
                for (int sh = 1; sh < 16; sh <<= 1) mx = fmaxf(mx, __shfl_xor(mx, sh));
                if (lane15 == 0) sR[rowl * 4 + wk] = mx;
            }
        __syncthreads();                     // (A)
        if (tid < 64) {
            const float m_old = sM[tid];
            float mn = m_old;
            #pragma unroll
            for (int ww = 0; ww < 4; ++ww) mn = fmaxf(mn, sR[tid * 4 + ww]);
            sMn[tid] = mn; sAl[tid] = __expf(m_old - mn); sM[tid] = mn;
        }
        __syncthreads();                     // (B)

        // ---- P = exp(S-m) -> LDS (STATIC indices); rescale O; row sums ----
        #pragma unroll
        for (int mi = 0; mi < 2; ++mi)
            #pragma unroll
            for (int r = 0; r < 4; ++r) {
                const int rowl = wq * 32 + mi * 16 + quad * 4 + r;
                const float mn = sMn[rowl], al = sAl[rowl];
                float sum = 0.f;
                #pragma unroll
                for (int ni = 0; ni < 2; ++ni) {
                    const float p = __expf(Sacc[mi][ni][r] - mn);
                    sP[rowl * 136 + wk * 32 + ni * 16 + lane15] = f2bf(p);
                    sum += p;
                }
                #pragma unroll
                for (int ci = 0; ci < 8; ++ci) Oacc[mi][ci][r] *= al;
                #pragma unroll
                for (int sh = 1; sh < 16; sh <<= 1) sum += __shfl_xor(sum, sh);
                if (lane15 == 0) sR[rowl * 4 + wk] = sum;
            }
        __syncthreads();                     // (C): sR + sP visible
        if (tid < 64) {
            float s = 0.f;
            #pragma unroll
            for (int ww = 0; ww < 4; ++ww) s += sR[tid * 4 + ww];
            sL[tid] = sL[tid] * sAl[tid] + s;
        }
        // prefetch V chunk 0 (512 c-rows x 32 t) into sKV[1]
        #pragma unroll
        for (int jj = 0; jj < 4; ++jj) {
            const int c = jj * 128 + (tid >> 2);
            const u16* g = KVT + (size_t)(b * 512 + c) * S_ + kt + seg8;
            u16* ld = &sKV[1][jj * 4096 + (tid >> 2) * 32 + seg8];
            __builtin_amdgcn_global_load_lds((const AS1 unsigned*)g, (AS3 unsigned*)ld, 16, 0, 0);
        }

        // ---- PV: O(64x512) += P(64x128) . KV(128x512), 4 t-chunks of 32 ----
        #pragma unroll 1
        for (int tc = 0; tc < 4; ++tc) {
            const int cur = (tc + 1) & 1;    // V chunk tc lives in sKV[(tc+1)&1]
            __syncthreads();                 // drain V[tc] loads (+ sP for tc=0)
            if (tc < 3) {
                #pragma unroll
                for (int jj = 0; jj < 4; ++jj) {
                    const int c = jj * 128 + (tid >> 2);
                    const u16* g = KVT + (size_t)(b * 512 + c) * S_ + kt + (tc + 1) * 32 + seg8;
                    u16* ld = &sKV[cur ^ 1][jj * 4096 + (tid >> 2) * 32 + seg8];
                    __builtin_amdgcn_global_load_lds((const AS1 unsigned*)g, (AS3 unsigned*)ld, 16, 0, 0);
                }
            }
            s16x8 pf[2], vf[8];
            #pragma unroll
            for (int mi = 0; mi < 2; ++mi)
                pf[mi] = *(const s16x8*)&sP[(wq * 32 + mi * 16 + lane15) * 136 + tc * 32 + quad * 8];
            #pragma unroll
            for (int ci = 0; ci < 8; ++ci)
                vf[ci] = *(const s16x8*)&sKV[cur][(wk * 128 + ci * 16 + lane15) * 32 + quad * 8];
            #pragma unroll
            for (int mi = 0; mi < 2; ++mi)
                #pragma unroll
                for (int ci = 0; ci < 8; ++ci)
                    Oacc[mi][ci] = __builtin_amdgcn_mfma_f32_16x16x32_bf16(pf[mi], vf[ci], Oacc[mi][ci], 0, 0, 0);
        }
    }

    // ---- epilogue: O/l -> bf16, overwrite Qpack[..., 0:512] ----
    __syncthreads();
    #pragma unroll
    for (int mi = 0; mi < 2; ++mi)
        #pragma unroll
        for (int r = 0; r < 4; ++r) {
            const int rowl = wq * 32 + mi * 16 + quad * 4 + r;
            const float inv = 1.f / sL[rowl];
            #pragma unroll
            for (int ci = 0; ci < 8; ++ci)
                Qrow[(size_t)rowl * 576 + wk * 128 + ci * 16 + lane15] =
                    f2bf(Oacc[mi][ci][r] * inv);
        }
}

// ---------------------------------------------------------------------------
__global__ __launch_bounds__(256)
void cast_f32_bf16(const float* __restrict__ src, u16* __restrict__ dst, int n)
{
    for (int i = blockIdx.x * 256 + threadIdx.x; i < n; i += gridDim.x * 256)
        dst[i] = f2bf(src[i]);
}

__global__ __launch_bounds__(256)
void prep_wbnT(const float* __restrict__ wkvb, u16* __restrict__ dst)
{
    int i = blockIdx.x * 256 + threadIdx.x;
    int h = i >> 16, rem = i & 65535, c = rem >> 7, d = rem & 127;
    dst[i] = f2bf(wkvb[(size_t)(h * 256 + d) * 512 + c]);
}

__global__ __launch_bounds__(256)
void prep_wbv(const float* __restrict__ wkvb, u16* __restrict__ dst)
{
    int i = blockIdx.x * 256 + threadIdx.x;
    int h = i >> 16, rem = i & 65535;
    dst[i] = f2bf(wkvb[(size_t)h * 131072 + 65536 + rem]);
}

__global__ __launch_bounds__(256)
void rmsnorm_bf16(u16* __restrict__ X, const float* __restrict__ w, int D)
{
    const int m = blockIdx.x;
    u16* x = X + (size_t)m * D;
    float ss = 0.f;
    for (int k = threadIdx.x; k < D; k += 256) { float v = bf2f(x[k]); ss += v * v; }
    __shared__ float red[256];
    red[threadIdx.x] = ss; __syncthreads();
    for (int s = 128; s > 0; s >>= 1) {
        if (threadIdx.x < s) red[threadIdx.x] += red[threadIdx.x + s];
        __syncthreads();
    }
    const float sc = rsqrtf(red[0] / (float)D + 1e-6f);
    for (int k = threadIdx.x; k < D; k += 256) x[k] = f2bf(bf2f(x[k]) * sc * w[k]);
}

// q (bf16, rows QSTR) -> rotate q_pe, write to Qpack[h][m][512:576]
__global__ __launch_bounds__(256)
void rope_q(const u16* __restrict__ q, const float* __restrict__ freqs, u16* __restrict__ Qp)
{
    const int idx = blockIdx.x * 256 + threadIdx.x;
    const int i = idx & 31, h = (idx >> 5) & 15, m = idx >> 9;
    const int s = m & (S_ - 1);
    const float c = freqs[(s * 32 + i) * 2], sn = freqs[(s * 32 + i) * 2 + 1];
    const u16* src = q + (size_t)m * QSTR + h * QKH_ + QKN_ + 2 * i;
    const float x0 = bf2f(src[0]), x1 = bf2f(src[1]);
    u16* dst = Qp + ((size_t)h * M_TOT + m) * 576 + 512 + 2 * i;
    dst[0] = f2bf(x0 * c - x1 * sn);
    dst[1] = f2bf(x1 * c + x0 * sn);
}

__global__ __launch_bounds__(256)
void kv_norm_rope(const u16* __restrict__ kva, const float* __restrict__ w,
                  const float* __restrict__ freqs, u16* __restrict__ Kcat)
{
    const int m = blockIdx.x, s = m & (S_ - 1);
    const u16* x = kva + (size_t)m * 576;
    float ss = 0.f;
    for (int k = threadIdx.x; k < 512; k += 256) { float v = bf2f(x[k]); ss += v * v; }
    __shared__ float red[256];
    red[threadIdx.x] = ss; __syncthreads();
    for (int st = 128; st > 0; st >>= 1) {
        if (threadIdx.x < st) red[threadIdx.x] += red[threadIdx.x + st];
        __syncthreads();
    }
    const float sc = rsqrtf(red[0] / 512.f + 1e-6f);
    for (int k = threadIdx.x; k < 512; k += 256)
        Kcat[(size_t)m * 576 + k] = f2bf(bf2f(x[k]) * sc * w[k]);
    if (threadIdx.x < 32) {
        const int i = threadIdx.x;
        const float c = freqs[(s * 32 + i) * 2], sn = freqs[(s * 32 + i) * 2 + 1];
        const float x0 = bf2f(x[512 + 2 * i]), x1 = bf2f(x[512 + 2 * i + 1]);
        Kcat[(size_t)m * 576 + 512 + 2 * i]     = f2bf(x0 * c - x1 * sn);
        Kcat[(size_t)m * 576 + 512 + 2 * i + 1] = f2bf(x1 * c + x0 * sn);
    }
}

__global__ __launch_bounds__(256)
void transpose_kv(const u16* __restrict__ Kcat, u16* __restrict__ KVT)
{
    __shared__ u16 t[64][65];
    const int s0 = blockIdx.x * 64, c0 = blockIdx.y * 64, b = blockIdx.z;
    #pragma unroll
    for (int i = 0; i < 16; ++i) {
        int id = i * 256 + threadIdx.x, r = id >> 6, c = id & 63;
        t[r][c] = Kcat[(size_t)(b * S_ + s0 + r) * 576 + c0 + c];
    }
    __syncthreads();
    #pragma unroll
    for (int i = 0; i < 16; ++i) {
        int id = i * 256 + threadIdx.x, r = id >> 6, c = id & 63;
        KVT[(size_t)(b * 512 + c0 + r) * S_ + s0 + c] = t[c][r];
    }
}

// ---------------------------------------------------------------------------
extern "C" void kernel_launch(void* const* d_in, const int* in_sizes, int n_in,
                              void* d_out, int out_size, void* d_ws, size_t ws_size,
                              hipStream_t stream)
{
    (void)in_sizes; (void)n_in; (void)out_size; (void)ws_size;
    const float* x         = (const float*)d_in[0];
    const float* freqs     = (const float*)d_in[1];
    const float* wq_a_w    = (const float*)d_in[4];
    const float* wq_a_b    = (const float*)d_in[5];
    const float* q_norm_w  = (const float*)d_in[6];
    const float* wq_b_w    = (const float*)d_in[7];
    const float* wq_b_b    = (const float*)d_in[8];
    const float* wkv_a_w   = (const float*)d_in[9];
    const float* wkv_a_b   = (const float*)d_in[10];
    const float* kv_norm_w = (const float*)d_in[11];
    const float* wkv_b_w   = (const float*)d_in[12];
    const float* wo_w      = (const float*)d_in[13];
    const float* wo_b      = (const float*)d_in[14];
    float* out = (float*)d_out;

    char* W = (char*)d_ws;
    u16* x_bf  = (u16*)(W + 0);
    u16* wqa   = (u16*)(W + 16777216);
    u16* wqb   = (u16*)(W + 23068672);
    u16* wkva  = (u16*)(W + 32505856);
    u16* wobf  = (u16*)(W + 34865152);
    u16* wbnT  = (u16*)(W + 43253760);
    u16* wbv   = (u16*)(W + 45350912);
    u16* q_a   = (u16*)(W + 47448064);
    u16* q     = (u16*)(W + 60030976);
    u16* kv_a  = (u16*)(W + 85196800);
    u16* Kcat  = (u16*)(W + 89915392);
    u16* KVT   = (u16*)(W + 94633984);
    u16* Qp    = (u16*)(W + 98828288);   // Qpack[h][4096][576]: q_abs|q_pe -> attn out
    u16* outh  = (u16*)(W + 174325760);

    const dim3 blk(256);

    // --- dtype prep ---
    cast_f32_bf16<<<2048, blk, 0, stream>>>(x, x_bf, M_TOT * DIM_);
    cast_f32_bf16<<<2048, blk, 0, stream>>>(wq_a_w, wqa, QL_ * DIM_);
    cast_f32_bf16<<<2048, blk, 0, stream>>>(wq_b_w, wqb, QSTR * QL_);
    cast_f32_bf16<<<2048, blk, 0, stream>>>(wkv_a_w, wkva, 576 * DIM_);
    cast_f32_bf16<<<2048, blk, 0, stream>>>(wo_w, wobf, DIM_ * DIM_);
    prep_wbnT<<<4096, blk, 0, stream>>>(wkv_b_w, wbnT);
    prep_wbv<<<4096, blk, 0, stream>>>(wkv_b_w, wbv);

    // --- q path ---
    gemm_bf16<<<dim3(12, 32, 1), blk, 0, stream>>>(x_bf, wqa, wq_a_b, q_a,
        M_TOT, QL_, DIM_, DIM_, DIM_, QL_, 0, 0, 0, 1.f, 0);
    rmsnorm_bf16<<<M_TOT, blk, 0, stream>>>(q_a, q_norm_w, QL_);
    gemm_bf16<<<dim3(24, 32, 1), blk, 0, stream>>>(q_a, wqb, wq_b_b, q,
        M_TOT, QSTR, QL_, QL_, QL_, QSTR, 0, 0, 0, 1.f, 0);
    rope_q<<<(M_TOT * NH_ * 32) / 256, blk, 0, stream>>>(q, freqs, Qp);

    // --- kv path ---
    gemm_bf16<<<dim3(5, 32, 1), blk, 0, stream>>>(x_bf, wkva, wkv_a_b, kv_a,
        M_TOT, 576, DIM_, DIM_, DIM_, 576, 0, 0, 0, 1.f, 0);
    kv_norm_rope<<<M_TOT, blk, 0, stream>>>(kv_a, kv_norm_w, freqs, Kcat);
    transpose_kv<<<dim3(32, 8, 2), blk, 0, stream>>>(Kcat, KVT);

    // --- q absorb: Qpack[h][m][0:512] = q_nope @ wkv_b[h,:128,:] ---
    gemm_bf16<<<dim3(4, 32, 16), blk, 0, stream>>>(q, wbnT, nullptr, Qp,
        M_TOT, 512, 128, QSTR, 128, 576, QKH_, 65536, (long long)M_TOT * 576, 1.f, 0);

    // --- fused flash attention v3 ---
    mla_flash<<<dim3(32, 16, 2), dim3(512), 0, stream>>>(Qp, Kcat, KVT);

    // --- V projection: outh[m][h*128+d] = O[h][m][:] . wbv[h][d][:] ---
    gemm_bf16<<<dim3(1, 32, 16), blk, 0, stream>>>(Qp, wbv, nullptr, outh,
        M_TOT, VH_, 512, 576, 512, DIM_, (long long)M_TOT * 576, 65536, VH_, 1.f, 0);

    // --- output projection (fp32 out) ---
    gemm_bf16<<<dim3(16, 32, 1), blk, 0, stream>>>(outh, wobf, wo_b, out,
        M_TOT, DIM_, DIM_, DIM_, DIM_, DIM_, 0, 0, 0, 1.f, 1);
}